// Round 1
// baseline (250.790 us; speedup 1.0000x reference)
//
#include <hip/hip_runtime.h>

// PyramidROIAlign: B=2, N=1000, C=256, pool 7x7.
// fmaps: P2 [B,256,256,C], P3 [B,128,128,C], P4 [B,64,64,C], P5 [B,32,32,C], f32.
// Output [B,N,7,7,C] f32.
//
// One 64-lane wave per pool cell (box, py, px); lane handles 4 channels via
// float4 -> 4 coalesced corner loads + 1 coalesced store per lane.

#define POOL 7
#define CCH 256

__global__ __launch_bounds__(256) void roi_align_kernel(
    const float* __restrict__ boxes,   // [B*N, 4] y1,x1,y2,x2
    const float* __restrict__ ish,     // [2]
    const float* __restrict__ P2,
    const float* __restrict__ P3,
    const float* __restrict__ P4,
    const float* __restrict__ P5,
    float* __restrict__ out,           // [B*N, 7, 7, C]
    int n_cells, int N)
{
    int cell = blockIdx.x * 4 + (threadIdx.x >> 6);
    if (cell >= n_cells) return;
    int lane = threadIdx.x & 63;

    int px  = cell % POOL;
    int t   = cell / POOL;
    int py  = t % POOL;
    int n   = t / POOL;          // flat box index in [0, B*N)
    int b   = n / N;             // batch index

    float y1 = boxes[n * 4 + 0];
    float x1 = boxes[n * 4 + 1];
    float y2 = boxes[n * 4 + 2];
    float x2 = boxes[n * 4 + 3];
    float h = y2 - y1;
    float w = x2 - x1;

    // compute_roi_level — replicate reference expression order exactly.
    float area = ish[0] * ish[1];
    float lvl  = log2f(sqrtf(h * w) / (224.0f / sqrtf(area)));
    float Lf   = fminf(5.0f, fmaxf(2.0f, 4.0f + rintf(lvl)));  // rintf = round-half-even, matches np.round
    int   L    = (int)Lf;

    const float* fmap;
    int H;
    if (L == 2)      { fmap = P2; H = 256; }
    else if (L == 3) { fmap = P3; H = 128; }
    else if (L == 4) { fmap = P4; H = 64;  }
    else             { fmap = P5; H = 32;  }
    int W = H;

    // crop_and_resize sampling point
    float gy = (float)py / (float)(POOL - 1);
    float gx = (float)px / (float)(POOL - 1);
    float in_y = (y1 + h * gy) * (float)(H - 1);
    float in_x = (x1 + w * gx) * (float)(W - 1);
    float y0f = floorf(in_y);
    float x0f = floorf(in_x);
    float wy = in_y - y0f;
    float wx = in_x - x0f;
    int y0  = min(max((int)y0f, 0), H - 1);
    int y1i = min(y0 + 1, H - 1);
    int x0  = min(max((int)x0f, 0), W - 1);
    int x1i = min(x0 + 1, W - 1);

    size_t base = (size_t)b * H * W * CCH;
    const float* ptl = fmap + base + ((size_t)y0  * W + x0 ) * CCH;
    const float* ptr = fmap + base + ((size_t)y0  * W + x1i) * CCH;
    const float* pbl = fmap + base + ((size_t)y1i * W + x0 ) * CCH;
    const float* pbr = fmap + base + ((size_t)y1i * W + x1i) * CCH;

    int c = lane * 4;
    float4 tl = *(const float4*)(ptl + c);
    float4 tr = *(const float4*)(ptr + c);
    float4 bl = *(const float4*)(pbl + c);
    float4 br = *(const float4*)(pbr + c);

    float4 o;
    {
        float top, bot;
        top = tl.x + (tr.x - tl.x) * wx;
        bot = bl.x + (br.x - bl.x) * wx;
        o.x = top + (bot - top) * wy;
        top = tl.y + (tr.y - tl.y) * wx;
        bot = bl.y + (br.y - bl.y) * wx;
        o.y = top + (bot - top) * wy;
        top = tl.z + (tr.z - tl.z) * wx;
        bot = bl.z + (br.z - bl.z) * wx;
        o.z = top + (bot - top) * wy;
        top = tl.w + (tr.w - tl.w) * wx;
        bot = bl.w + (br.w - bl.w) * wx;
        o.w = top + (bot - top) * wy;
    }

    *(float4*)(out + (size_t)cell * CCH + c) = o;
}

extern "C" void kernel_launch(void* const* d_in, const int* in_sizes, int n_in,
                              void* d_out, int out_size, void* d_ws, size_t ws_size,
                              hipStream_t stream)
{
    const float* boxes = (const float*)d_in[0];
    const float* ish   = (const float*)d_in[1];
    const float* P2    = (const float*)d_in[2];
    const float* P3    = (const float*)d_in[3];
    const float* P4    = (const float*)d_in[4];
    const float* P5    = (const float*)d_in[5];
    float* out = (float*)d_out;

    int total_boxes = in_sizes[0] / 4;                  // B*N = 2000
    int B = in_sizes[2] / (256 * 256 * CCH);            // P2 is [B,256,256,C]
    int N = total_boxes / B;
    int n_cells = total_boxes * POOL * POOL;            // 98000

    int blocks = (n_cells + 3) / 4;                     // 4 cells (waves) per 256-thread block
    roi_align_kernel<<<blocks, 256, 0, stream>>>(boxes, ish, P2, P3, P4, P5,
                                                 out, n_cells, N);
}